// Round 11
// baseline (1683.732 us; speedup 1.0000x reference)
//
#include <hip/hip_runtime.h>
#include <stdint.h>

#define M_DIM 8192
#define N_DIM 4096
#define K_DIM 4096
#define NT2 (K_DIM / 64)  // 64 k-tiles of 64 fp8 bytes

typedef float f32x4 __attribute__((ext_vector_type(4)));
typedef float f32x16 __attribute__((ext_vector_type(16)));
typedef int v4i __attribute__((ext_vector_type(4)));
typedef int v8i __attribute__((ext_vector_type(8)));
typedef uint32_t u32;

// ---------- helpers ----------

__device__ __forceinline__ void gload_lds16(const void* g, void* l) {
  __builtin_amdgcn_global_load_lds(
      (__attribute__((address_space(1))) void*)(g),
      (__attribute__((address_space(3))) void*)(l), 16, 0, 0);
}

__device__ __forceinline__ float clipmul(float v, float rs) {
  v = v * rs;
  return fminf(fmaxf(v, -448.f), 448.f);
}

__device__ __forceinline__ u32 pack4_fp8(float a, float b, float c, float d) {
  int w = __builtin_amdgcn_cvt_pk_fp8_f32(a, b, 0, false);
  w = __builtin_amdgcn_cvt_pk_fp8_f32(c, d, w, true);
  return (u32)w;
}

__device__ __forceinline__ v8i rd8(const void* lo, const void* hi) {
  v4i l = *(const v4i*)lo;
  v4i h = *(const v4i*)hi;
  return __builtin_shufflevector(l, h, 0, 1, 2, 3, 4, 5, 6, 7);
}

__device__ __forceinline__ f32x16 mfma32(v8i a, v8i b, f32x16 c) {
  return __builtin_amdgcn_mfma_scale_f32_32x32x64_f8f6f4(
      a, b, c, 0, 0, 0, 0x7f7f7f7f, 0, 0x7f7f7f7f);
}

// ---------- quantize A (row-major M x K, f32 -> e4m3fn) ----------
// Division hoisted: one rcp per thread, multiply per element (the per-element
// v_div sequence was ~10 VALU ops x 134M elements).

__global__ __launch_bounds__(256) void quant_a(const float* __restrict__ x,
                                               u32* __restrict__ q,
                                               const float* __restrict__ scale,
                                               int nv4) {
  int base = blockIdx.x * 1024 + threadIdx.x;
  float rs = 1.0f / scale[0];
#pragma unroll
  for (int r = 0; r < 4; ++r) {
    int idx = base + r * 256;
    if (idx < nv4) {
      float4 v = ((const float4*)x)[idx];
      q[idx] = pack4_fp8(clipmul(v.x, rs), clipmul(v.y, rs),
                         clipmul(v.z, rs), clipmul(v.w, rs));
    }
  }
}

// ---------- quantize + transpose B (K x N f32 -> N x K fp8), u32-packed ----

__global__ __launch_bounds__(256) void quant_b_t(const float* __restrict__ B,
                                                 uint8_t* __restrict__ qT,
                                                 const float* __restrict__ scale) {
  __shared__ u32 lt[64 * 17];  // 64 n-rows x 16 dwords + 1 pad
  int tid = threadIdx.x;
  int kt = blockIdx.x * 64;
  int nt = blockIdx.y * 64;
  float rs = 1.0f / scale[0];

  int kq = tid >> 4;  // 0..15 -> k0 = 4*kq
  int nq = tid & 15;  // 0..15 -> n0 = 4*nq
  int k0 = kq * 4, n0 = nq * 4;
  const float* src = B + (long)(kt + k0) * N_DIM + nt + n0;
  float4 v0 = *(const float4*)(src);
  float4 v1 = *(const float4*)(src + N_DIM);
  float4 v2 = *(const float4*)(src + 2 * N_DIM);
  float4 v3 = *(const float4*)(src + 3 * N_DIM);

  lt[(n0 + 0) * 17 + kq] = pack4_fp8(clipmul(v0.x, rs), clipmul(v1.x, rs),
                                     clipmul(v2.x, rs), clipmul(v3.x, rs));
  lt[(n0 + 1) * 17 + kq] = pack4_fp8(clipmul(v0.y, rs), clipmul(v1.y, rs),
                                     clipmul(v2.y, rs), clipmul(v3.y, rs));
  lt[(n0 + 2) * 17 + kq] = pack4_fp8(clipmul(v0.z, rs), clipmul(v1.z, rs),
                                     clipmul(v2.z, rs), clipmul(v3.z, rs));
  lt[(n0 + 3) * 17 + kq] = pack4_fp8(clipmul(v0.w, rs), clipmul(v1.w, rs),
                                     clipmul(v2.w, rs), clipmul(v3.w, rs));
  __syncthreads();

  int n = tid >> 2, ch = tid & 3;
  uint4 o;
  o.x = lt[n * 17 + ch * 4 + 0];
  o.y = lt[n * 17 + ch * 4 + 1];
  o.z = lt[n * 17 + ch * 4 + 2];
  o.w = lt[n * 17 + ch * 4 + 3];
  *(uint4*)&qT[(long)(nt + n) * K_DIM + kt + ch * 16] = o;
}

// ---------- 256x256 MX-fp8 GEMM, 32x32x64, BK=64, 2 wgs/CU ----------
// r9's proven coarse schedule (stage-first, compute, single vmcnt(0)+barrier
// per K-tile) with BK 128->64: LDS halves to 64 KiB -> TWO co-resident wgs
// per CU (16 waves). When one wg sits in its drain/barrier, the other feeds
// the MFMA pipe (m114 overlap) — the advantage r2/r6 had that r9 lost, now
// combined with r9's minimal read-amplification (12 ds_read_b128 + 8 mfma32
// per wave per 64B K-tile; same reads/FLOP as r9).
// LDS: A bufs [0,16K),[16K,32K); B bufs [32K,48K),[48K,64K).
// 64B rows = 4 granules of 16B; swizzle g_phys = g ^ ((row>>1)&3): 8
// consecutive rows hit 8 distinct 4-bank groups (bandwidth floor only).
// Stage keeps linear LDS dest + pre-swizzled global source (rule #21).
// WAR: stage targets buf^1; all reads of buf retire before each wave's
// MFMAs (lgkmcnt) hence before the barrier. RAW: vmcnt(0) before barrier.

template <int BUF>
__device__ __forceinline__ void stage_tile(const uint8_t* const (&gA)[2],
                                           const uint8_t* const (&gB)[2],
                                           uint8_t* lds, const int (&ldo)[2],
                                           long ko) {
#pragma unroll
  for (int r = 0; r < 2; ++r)
    gload_lds16(gA[r] + ko, lds + BUF * 16384 + ldo[r]);
#pragma unroll
  for (int r = 0; r < 2; ++r)
    gload_lds16(gB[r] + ko, lds + 32768 + BUF * 16384 + ldo[r]);
}

template <int BUF>
__device__ __forceinline__ void compute_tile(const uint8_t* lds,
                                             const int (&offA)[4][2],
                                             const int (&offB)[2][2],
                                             f32x16 (&acc)[4][2]) {
  const uint8_t* Ab = lds + BUF * 16384;
  const uint8_t* Bb = lds + 32768 + BUF * 16384;
  v8i a[4], b[2];
#pragma unroll
  for (int nj = 0; nj < 2; ++nj)
    b[nj] = rd8(Bb + offB[nj][0], Bb + offB[nj][1]);
#pragma unroll
  for (int mi = 0; mi < 4; ++mi)
    a[mi] = rd8(Ab + offA[mi][0], Ab + offA[mi][1]);
#pragma unroll
  for (int mi = 0; mi < 4; ++mi)
#pragma unroll
    for (int nj = 0; nj < 2; ++nj)
      acc[mi][nj] = mfma32(a[mi], b[nj], acc[mi][nj]);
}

__global__ __launch_bounds__(512, 4) void gemm_mx(const uint8_t* __restrict__ Aq,
                                                  const uint8_t* __restrict__ BqT,
                                                  float* __restrict__ C,
                                                  const float* __restrict__ sA,
                                                  const float* __restrict__ sB) {
  __shared__ __align__(16) uint8_t lds[65536];

  const int tid = threadIdx.x;
  const int lane = tid & 63;
  const int wid = tid >> 6;
  const int wr = wid >> 2;  // 0..1: 128-row strip of A
  const int wc = wid & 3;   // 0..3: 64-col strip of B
  const int l31 = lane & 31;
  const int hi2 = lane >> 5;  // 0..1

  // XCD-aware swizzle: 512 wgs, 64 per XCD chunk (bijective, 512%8==0)
  int bid = blockIdx.x;
  int wg = (bid & 7) * 64 + (bid >> 3);
  const long bm = (long)(wg >> 4) * 256;  // 32 M-tiles
  const long bn = (long)(wg & 15) * 256;  // 16 N-tiles

  // scales: materialize before staging so their loads never sit in the vmem
  // queue during the counted waits.
  float s = sA[0] * sB[0];
  asm volatile("" ::"v"(s));

  // --- staging: 1024 granules per matrix per tile, 2 per thread ---
  const uint8_t* gA[2];
  const uint8_t* gB[2];
  int ldo[2];
#pragma unroll
  for (int r = 0; r < 2; ++r) {
    int gid = tid + 512 * r;            // 0..1023
    int row = gid >> 2, gc = gid & 3;   // 256 rows x 4 granules
    int sc = (gc ^ ((row >> 1) & 3)) << 4;  // pre-swizzled source granule
    gA[r] = Aq + (bm + row) * (long)K_DIM + sc;
    gB[r] = BqT + (bn + row) * (long)K_DIM + sc;
    ldo[r] = gid * 16;  // linear LDS dest
  }

  // --- fragment read offsets (loop-invariant, swizzled) ---
  int offA[4][2], offB[2][2];
#pragma unroll
  for (int mi = 0; mi < 4; ++mi) {
    int ra = wr * 128 + mi * 32 + l31;  // 0..255
#pragma unroll
    for (int j = 0; j < 2; ++j) {
      int g = hi2 * 2 + j;
      offA[mi][j] = ra * 64 + ((g ^ ((ra >> 1) & 3)) << 4);
    }
  }
#pragma unroll
  for (int nj = 0; nj < 2; ++nj) {
    int rb = wc * 64 + nj * 32 + l31;  // 0..255
#pragma unroll
    for (int j = 0; j < 2; ++j) {
      int g = hi2 * 2 + j;
      offB[nj][j] = rb * 64 + ((g ^ ((rb >> 1) & 3)) << 4);
    }
  }

  f32x16 acc[4][2] = {};

  // ---- prologue ----
  stage_tile<0>(gA, gB, lds, ldo, 0);
  asm volatile("s_waitcnt vmcnt(0)" ::: "memory");
  __builtin_amdgcn_s_barrier();

  // ---- main loop: 2 K-tiles per iteration, static buffer indices ----
  for (int i = 0; i < NT2 / 2; ++i) {
    long ko1 = (long)((2 * i + 1) & (NT2 - 1)) * 64;
    stage_tile<1>(gA, gB, lds, ldo, ko1);   // issue first
    compute_tile<0>(lds, offA, offB, acc);  // 12 reads + 8 MFMA per wave
    asm volatile("s_waitcnt vmcnt(0)" ::: "memory");
    __builtin_amdgcn_s_barrier();

    long ko2 = (long)((2 * i + 2) & (NT2 - 1)) * 64;  // wraps harmlessly
    stage_tile<0>(gA, gB, lds, ldo, ko2);
    compute_tile<1>(lds, offA, offB, acc);
    asm volatile("s_waitcnt vmcnt(0)" ::: "memory");
    __builtin_amdgcn_s_barrier();
  }

  // ---- epilogue: C-write (32x32 C/D layout) ----
#pragma unroll
  for (int mi = 0; mi < 4; ++mi)
#pragma unroll
    for (int nj = 0; nj < 2; ++nj) {
      f32x16 v = acc[mi][nj];
      long col = bn + wc * 64 + nj * 32 + l31;
#pragma unroll
      for (int q = 0; q < 16; ++q) {
        long row = bm + wr * 128 + mi * 32 + (q & 3) + 8 * (q >> 2) + 4 * hi2;
        C[row * N_DIM + col] = v[q] * s;
      }
    }
}

// ---------- launcher ----------

extern "C" void kernel_launch(void* const* d_in, const int* in_sizes, int n_in,
                              void* d_out, int out_size, void* d_ws, size_t ws_size,
                              hipStream_t stream) {
  const float* A = (const float*)d_in[0];   // (8192, 4096)
  const float* B = (const float*)d_in[1];   // (4096, 4096)
  const float* sA = (const float*)d_in[2];  // input_scale
  const float* sB = (const float*)d_in[4];  // kernel_scale
  float* out = (float*)d_out;

  uint8_t* Aq = (uint8_t*)d_ws;               // M*K fp8
  uint8_t* BqT = Aq + (size_t)M_DIM * K_DIM;  // N*K fp8 (transposed)

  int nv4_a = M_DIM * K_DIM / 4;
  quant_a<<<nv4_a / 1024, 256, 0, stream>>>(A, (u32*)Aq, sA, nv4_a);
  quant_b_t<<<dim3(K_DIM / 64, N_DIM / 64), 256, 0, stream>>>(B, BqT, sB);
  gemm_mx<<<dim3((M_DIM / 256) * (N_DIM / 256)), 512, 0, stream>>>(Aq, BqT, out, sA, sB);
}

// Round 12
// 201.050 us; speedup vs baseline: 8.3747x; 8.3747x over previous
//
#include <hip/hip_runtime.h>
#include <stdint.h>

#define M_DIM 8192
#define N_DIM 4096
#define K_DIM 4096
#define NT2 (K_DIM / 64)  // 64 k-tiles of 64 fp8 bytes

typedef float f32x4 __attribute__((ext_vector_type(4)));
typedef float f32x16 __attribute__((ext_vector_type(16)));
typedef int v4i __attribute__((ext_vector_type(4)));
typedef int v8i __attribute__((ext_vector_type(8)));
typedef uint32_t u32;

// ---------- helpers ----------

__device__ __forceinline__ void gload_lds16(const void* g, void* l) {
  __builtin_amdgcn_global_load_lds(
      (__attribute__((address_space(1))) void*)(g),
      (__attribute__((address_space(3))) void*)(l), 16, 0, 0);
}

__device__ __forceinline__ float clipmul(float v, float rs) {
  v = v * rs;
  return fminf(fmaxf(v, -448.f), 448.f);
}

__device__ __forceinline__ u32 pack4_fp8(float a, float b, float c, float d) {
  int w = __builtin_amdgcn_cvt_pk_fp8_f32(a, b, 0, false);
  w = __builtin_amdgcn_cvt_pk_fp8_f32(c, d, w, true);
  return (u32)w;
}

__device__ __forceinline__ v8i rd8(const void* lo, const void* hi) {
  v4i l = *(const v4i*)lo;
  v4i h = *(const v4i*)hi;
  return __builtin_shufflevector(l, h, 0, 1, 2, 3, 4, 5, 6, 7);
}

__device__ __forceinline__ f32x16 mfma32(v8i a, v8i b, f32x16 c) {
  return __builtin_amdgcn_mfma_scale_f32_32x32x64_f8f6f4(
      a, b, c, 0, 0, 0, 0x7f7f7f7f, 0, 0x7f7f7f7f);
}

// ---------- quantize A (row-major M x K, f32 -> e4m3fn) ----------

__global__ __launch_bounds__(256) void quant_a(const float* __restrict__ x,
                                               u32* __restrict__ q,
                                               const float* __restrict__ scale,
                                               int nv4) {
  int base = blockIdx.x * 1024 + threadIdx.x;
  float rs = 1.0f / scale[0];
#pragma unroll
  for (int r = 0; r < 4; ++r) {
    int idx = base + r * 256;
    if (idx < nv4) {
      float4 v = ((const float4*)x)[idx];
      q[idx] = pack4_fp8(clipmul(v.x, rs), clipmul(v.y, rs),
                         clipmul(v.z, rs), clipmul(v.w, rs));
    }
  }
}

// ---------- quantize + transpose B (K x N f32 -> N x K fp8), u32-packed ----

__global__ __launch_bounds__(256) void quant_b_t(const float* __restrict__ B,
                                                 uint8_t* __restrict__ qT,
                                                 const float* __restrict__ scale) {
  __shared__ u32 lt[64 * 17];  // 64 n-rows x 16 dwords + 1 pad
  int tid = threadIdx.x;
  int kt = blockIdx.x * 64;
  int nt = blockIdx.y * 64;
  float rs = 1.0f / scale[0];

  int kq = tid >> 4;  // 0..15 -> k0 = 4*kq
  int nq = tid & 15;  // 0..15 -> n0 = 4*nq
  int k0 = kq * 4, n0 = nq * 4;
  const float* src = B + (long)(kt + k0) * N_DIM + nt + n0;
  float4 v0 = *(const float4*)(src);
  float4 v1 = *(const float4*)(src + N_DIM);
  float4 v2 = *(const float4*)(src + 2 * N_DIM);
  float4 v3 = *(const float4*)(src + 3 * N_DIM);

  lt[(n0 + 0) * 17 + kq] = pack4_fp8(clipmul(v0.x, rs), clipmul(v1.x, rs),
                                     clipmul(v2.x, rs), clipmul(v3.x, rs));
  lt[(n0 + 1) * 17 + kq] = pack4_fp8(clipmul(v0.y, rs), clipmul(v1.y, rs),
                                     clipmul(v2.y, rs), clipmul(v3.y, rs));
  lt[(n0 + 2) * 17 + kq] = pack4_fp8(clipmul(v0.z, rs), clipmul(v1.z, rs),
                                     clipmul(v2.z, rs), clipmul(v3.z, rs));
  lt[(n0 + 3) * 17 + kq] = pack4_fp8(clipmul(v0.w, rs), clipmul(v1.w, rs),
                                     clipmul(v2.w, rs), clipmul(v3.w, rs));
  __syncthreads();

  int n = tid >> 2, ch = tid & 3;
  uint4 o;
  o.x = lt[n * 17 + ch * 4 + 0];
  o.y = lt[n * 17 + ch * 4 + 1];
  o.z = lt[n * 17 + ch * 4 + 2];
  o.w = lt[n * 17 + ch * 4 + 3];
  *(uint4*)&qT[(long)(nt + n) * K_DIM + kt + ch * 16] = o;
}

// ---------- 256x256 MX-fp8 GEMM, 32x32x64, BK=64, 2 wgs/CU ----------
// Identical to round 11 EXCEPT __launch_bounds__(512, 2): r11's (512,4)
// forced a 64-VGPR cap, spilling the 128-reg accumulator to scratch
// (hbm_bytes 8.1 GB, MfmaUtil 3%). With (512,2) the compiler allocates
// ~128 VGPR (as in r7/r9/r10) and the 64 KiB LDS footprint alone yields
// 2 co-resident wgs/CU (160/64 = 2): r9's minimal read-amplification
// (12 ds_read_b128 + 8 mfma32 per wave per 64B K-tile) combined with the
// m114 cross-workgroup barrier-drain overlap that powered r2/r6.
// LDS: A bufs [0,16K),[16K,32K); B bufs [32K,48K),[48K,64K).
// 64B rows = 4 granules of 16B; swizzle g_phys = g ^ ((row>>1)&3); stage is
// linear-dest + pre-swizzled source (rule #21). WAR: stage targets buf^1,
// reads of buf retire before each wave's MFMAs hence before the barrier.
// RAW: vmcnt(0) before the barrier.

template <int BUF>
__device__ __forceinline__ void stage_tile(const uint8_t* const (&gA)[2],
                                           const uint8_t* const (&gB)[2],
                                           uint8_t* lds, const int (&ldo)[2],
                                           long ko) {
#pragma unroll
  for (int r = 0; r < 2; ++r)
    gload_lds16(gA[r] + ko, lds + BUF * 16384 + ldo[r]);
#pragma unroll
  for (int r = 0; r < 2; ++r)
    gload_lds16(gB[r] + ko, lds + 32768 + BUF * 16384 + ldo[r]);
}

template <int BUF>
__device__ __forceinline__ void compute_tile(const uint8_t* lds,
                                             const int (&offA)[4][2],
                                             const int (&offB)[2][2],
                                             f32x16 (&acc)[4][2]) {
  const uint8_t* Ab = lds + BUF * 16384;
  const uint8_t* Bb = lds + 32768 + BUF * 16384;
  v8i a[4], b[2];
#pragma unroll
  for (int nj = 0; nj < 2; ++nj)
    b[nj] = rd8(Bb + offB[nj][0], Bb + offB[nj][1]);
#pragma unroll
  for (int mi = 0; mi < 4; ++mi)
    a[mi] = rd8(Ab + offA[mi][0], Ab + offA[mi][1]);
#pragma unroll
  for (int mi = 0; mi < 4; ++mi)
#pragma unroll
    for (int nj = 0; nj < 2; ++nj)
      acc[mi][nj] = mfma32(a[mi], b[nj], acc[mi][nj]);
}

__global__ __launch_bounds__(512, 2) void gemm_mx(const uint8_t* __restrict__ Aq,
                                                  const uint8_t* __restrict__ BqT,
                                                  float* __restrict__ C,
                                                  const float* __restrict__ sA,
                                                  const float* __restrict__ sB) {
  __shared__ __align__(16) uint8_t lds[65536];

  const int tid = threadIdx.x;
  const int lane = tid & 63;
  const int wid = tid >> 6;
  const int wr = wid >> 2;  // 0..1: 128-row strip of A
  const int wc = wid & 3;   // 0..3: 64-col strip of B
  const int l31 = lane & 31;
  const int hi2 = lane >> 5;  // 0..1

  // XCD-aware swizzle: 512 wgs, 64 per XCD chunk (bijective, 512%8==0)
  int bid = blockIdx.x;
  int wg = (bid & 7) * 64 + (bid >> 3);
  const long bm = (long)(wg >> 4) * 256;  // 32 M-tiles
  const long bn = (long)(wg & 15) * 256;  // 16 N-tiles

  // scales: materialize before staging so their loads never sit in the vmem
  // queue during the counted waits.
  float s = sA[0] * sB[0];
  asm volatile("" ::"v"(s));

  // --- staging: 1024 granules per matrix per tile, 2 per thread ---
  const uint8_t* gA[2];
  const uint8_t* gB[2];
  int ldo[2];
#pragma unroll
  for (int r = 0; r < 2; ++r) {
    int gid = tid + 512 * r;            // 0..1023
    int row = gid >> 2, gc = gid & 3;   // 256 rows x 4 granules
    int sc = (gc ^ ((row >> 1) & 3)) << 4;  // pre-swizzled source granule
    gA[r] = Aq + (bm + row) * (long)K_DIM + sc;
    gB[r] = BqT + (bn + row) * (long)K_DIM + sc;
    ldo[r] = gid * 16;  // linear LDS dest
  }

  // --- fragment read offsets (loop-invariant, swizzled) ---
  int offA[4][2], offB[2][2];
#pragma unroll
  for (int mi = 0; mi < 4; ++mi) {
    int ra = wr * 128 + mi * 32 + l31;  // 0..255
#pragma unroll
    for (int j = 0; j < 2; ++j) {
      int g = hi2 * 2 + j;
      offA[mi][j] = ra * 64 + ((g ^ ((ra >> 1) & 3)) << 4);
    }
  }
#pragma unroll
  for (int nj = 0; nj < 2; ++nj) {
    int rb = wc * 64 + nj * 32 + l31;  // 0..255
#pragma unroll
    for (int j = 0; j < 2; ++j) {
      int g = hi2 * 2 + j;
      offB[nj][j] = rb * 64 + ((g ^ ((rb >> 1) & 3)) << 4);
    }
  }

  f32x16 acc[4][2] = {};

  // ---- prologue ----
  stage_tile<0>(gA, gB, lds, ldo, 0);
  asm volatile("s_waitcnt vmcnt(0)" ::: "memory");
  __builtin_amdgcn_s_barrier();

  // ---- main loop: 2 K-tiles per iteration, static buffer indices ----
  for (int i = 0; i < NT2 / 2; ++i) {
    long ko1 = (long)((2 * i + 1) & (NT2 - 1)) * 64;
    stage_tile<1>(gA, gB, lds, ldo, ko1);   // issue first
    compute_tile<0>(lds, offA, offB, acc);  // 12 reads + 8 MFMA per wave
    asm volatile("s_waitcnt vmcnt(0)" ::: "memory");
    __builtin_amdgcn_s_barrier();

    long ko2 = (long)((2 * i + 2) & (NT2 - 1)) * 64;  // wraps harmlessly
    stage_tile<0>(gA, gB, lds, ldo, ko2);
    compute_tile<1>(lds, offA, offB, acc);
    asm volatile("s_waitcnt vmcnt(0)" ::: "memory");
    __builtin_amdgcn_s_barrier();
  }

  // ---- epilogue: C-write (32x32 C/D layout) ----
#pragma unroll
  for (int mi = 0; mi < 4; ++mi)
#pragma unroll
    for (int nj = 0; nj < 2; ++nj) {
      f32x16 v = acc[mi][nj];
      long col = bn + wc * 64 + nj * 32 + l31;
#pragma unroll
      for (int q = 0; q < 16; ++q) {
        long row = bm + wr * 128 + mi * 32 + (q & 3) + 8 * (q >> 2) + 4 * hi2;
        C[row * N_DIM + col] = v[q] * s;
      }
    }
}

// ---------- launcher ----------

extern "C" void kernel_launch(void* const* d_in, const int* in_sizes, int n_in,
                              void* d_out, int out_size, void* d_ws, size_t ws_size,
                              hipStream_t stream) {
  const float* A = (const float*)d_in[0];   // (8192, 4096)
  const float* B = (const float*)d_in[1];   // (4096, 4096)
  const float* sA = (const float*)d_in[2];  // input_scale
  const float* sB = (const float*)d_in[4];  // kernel_scale
  float* out = (float*)d_out;

  uint8_t* Aq = (uint8_t*)d_ws;               // M*K fp8
  uint8_t* BqT = Aq + (size_t)M_DIM * K_DIM;  // N*K fp8 (transposed)

  int nv4_a = M_DIM * K_DIM / 4;
  quant_a<<<nv4_a / 1024, 256, 0, stream>>>(A, (u32*)Aq, sA, nv4_a);
  quant_b_t<<<dim3(K_DIM / 64, N_DIM / 64), 256, 0, stream>>>(B, BqT, sB);
  gemm_mx<<<dim3((M_DIM / 256) * (N_DIM / 256)), 512, 0, stream>>>(Aq, BqT, out, sA, sB);
}